// Round 3
// baseline (152.348 us; speedup 1.0000x reference)
//
#include <hip/hip_runtime.h>
#include <math.h>

using short8  = __attribute__((ext_vector_type(8))) short;
using floatx4 = __attribute__((ext_vector_type(4))) float;

__device__ __forceinline__ unsigned short f2bf(float x) {
  union { float f; unsigned u; } v; v.f = x;
  unsigned r = (v.u + 0x7FFFu + ((v.u >> 16) & 1u)) >> 16;
  return (unsigned short)r;
}

// ---------------- K1: Wh = h @ W  (f32 vector GEMM, 64x128 tile) ----------------
__global__ __launch_bounds__(256) void wh_gemm(
    const float* __restrict__ h, const float* __restrict__ W,
    float* __restrict__ Wh) {
  __shared__ __align__(16) float Al[16][64];    // [k][m]
  __shared__ __align__(16) float Bl[16][128];   // [k][n]
  const int m0 = blockIdx.x * 64;
  const int n0 = blockIdx.y * 128;
  const int t  = threadIdx.x;
  const int tx = t & 15, ty = t >> 4;
  float acc[4][8];
#pragma unroll
  for (int i = 0; i < 4; ++i)
#pragma unroll
    for (int j = 0; j < 8; ++j) acc[i][j] = 0.0f;

  for (int k0 = 0; k0 < 256; k0 += 16) {
    { // stage A (transpose to [k][m])
      int m = t & 63, kq = t >> 6;
      float4 v = *(const float4*)&h[(size_t)(m0 + m) * 256 + k0 + kq * 4];
      Al[kq * 4 + 0][m] = v.x; Al[kq * 4 + 1][m] = v.y;
      Al[kq * 4 + 2][m] = v.z; Al[kq * 4 + 3][m] = v.w;
    }
    { // stage B
      int n4 = t & 31, kr = t >> 5;
      *(float4*)&Bl[kr][n4 * 4]     = *(const float4*)&W[(size_t)(k0 + kr) * 256 + n0 + n4 * 4];
      *(float4*)&Bl[kr + 8][n4 * 4] = *(const float4*)&W[(size_t)(k0 + kr + 8) * 256 + n0 + n4 * 4];
    }
    __syncthreads();
#pragma unroll
    for (int k = 0; k < 16; ++k) {
      float4 av = *(const float4*)&Al[k][ty * 4];
      float4 b0 = *(const float4*)&Bl[k][tx * 4];
      float4 b1 = *(const float4*)&Bl[k][64 + tx * 4];
      float aa[4] = {av.x, av.y, av.z, av.w};
      float bb[8] = {b0.x, b0.y, b0.z, b0.w, b1.x, b1.y, b1.z, b1.w};
#pragma unroll
      for (int i = 0; i < 4; ++i)
#pragma unroll
        for (int j = 0; j < 8; ++j) acc[i][j] = fmaf(aa[i], bb[j], acc[i][j]);
    }
    __syncthreads();
  }
#pragma unroll
  for (int i = 0; i < 4; ++i) {
    size_t row = (size_t)(m0 + ty * 4 + i);
    float4 o0 = make_float4(acc[i][0], acc[i][1], acc[i][2], acc[i][3]);
    float4 o1 = make_float4(acc[i][4], acc[i][5], acc[i][6], acc[i][7]);
    *(float4*)&Wh[row * 256 + n0 + tx * 4]      = o0;
    *(float4*)&Wh[row * 256 + n0 + 64 + tx * 4] = o1;
  }
}

// ---------------- K2a: g[row] = Wh[row,:] . a2  (one wave per row) ----------------
__global__ __launch_bounds__(256) void g_rows(
    const float* __restrict__ Wh, const float* __restrict__ a,
    float* __restrict__ g) {
  int row = blockIdx.x * 4 + (threadIdx.x >> 6);
  int L = threadIdx.x & 63;
  float4 w  = *(const float4*)&Wh[(size_t)row * 256 + L * 4];
  float4 av = *(const float4*)&a[256 + L * 4];
  float d = w.x * av.x + w.y * av.y + w.z * av.z + w.w * av.w;
#pragma unroll
  for (int off = 32; off > 0; off >>= 1) d += __shfl_xor(d, off);
  if (L == 0) g[row] = d;
}

// ---------------- K2b: per-batch max of g ----------------
__global__ __launch_bounds__(256) void batch_max(
    const float* __restrict__ g, float* __restrict__ Mb) {
  __shared__ float red[4];
  int b = blockIdx.x, t = threadIdx.x;
  float m = -1e30f;
  for (int i = t; i < 2048; i += 256) m = fmaxf(m, g[(size_t)b * 2048 + i]);
#pragma unroll
  for (int off = 32; off > 0; off >>= 1) m = fmaxf(m, __shfl_xor(m, off));
  if ((t & 63) == 0) red[t >> 6] = m;
  __syncthreads();
  if (t == 0) Mb[b] = fmaxf(fmaxf(red[0], red[1]), fmaxf(red[2], red[3]));
}

// ---------------- K2c: Bt[b][c][j] = bf16(s_j * Wh[b,j,c]); col 256 = s_j; 257..287 = 0
__global__ __launch_bounds__(256) void build_bt(
    const float* __restrict__ Wh, const float* __restrict__ g,
    const float* __restrict__ Mb, unsigned short* __restrict__ Bt) {
  __shared__ __align__(16) unsigned short tile[288 * 64];  // [c][j]
  const int blk = blockIdx.x;
  const int b   = blk >> 5;
  const int j0  = (blk & 31) * 64;
  const int t   = threadIdx.x;
  const int j   = t & 63;
  const int q0  = t >> 6;
  const int row = b * 2048 + j0 + j;
  const float s = expf(g[row] - Mb[b]);
  for (int q = q0; q < 64; q += 4) {
    float4 wv = *(const float4*)&Wh[(size_t)row * 256 + q * 4];
    int c = q * 4;
    tile[(c + 0) * 64 + j] = f2bf(s * wv.x);
    tile[(c + 1) * 64 + j] = f2bf(s * wv.y);
    tile[(c + 2) * 64 + j] = f2bf(s * wv.z);
    tile[(c + 3) * 64 + j] = f2bf(s * wv.w);
  }
  if (q0 == 0) tile[256 * 64 + j] = f2bf(s);
  for (int z = t; z < 31 * 64; z += 256) tile[257 * 64 + z] = 0;
  __syncthreads();
#pragma unroll
  for (int p = 0; p < 9; ++p) {
    int id = t + 256 * p;          // 0..2303
    int c = id >> 3, off = id & 7;
    int4 v = *(const int4*)&tile[c * 64 + off * 8];
    *(int4*)((char*)Bt + (size_t)(b * 288 + c) * 4096 + j0 * 2 + off * 16) = v;
  }
}

// ---------------- K3: per batch:  [num|den] = adj @ Bt^T, epilogue div+elu -> out
// Barrier-free main loop: A and B fragments loaded direct-to-register, 2-deep
// software pipeline with named register sets (static indexing only).
__device__ __forceinline__ short8 pack_a(int4 v0, int4 v1) {
  union { uint4 u; short8 s; } r;
  r.u.x = ((unsigned)v0.x | ((unsigned)v0.y << 16)) * 0x3F80u;
  r.u.y = ((unsigned)v0.z | ((unsigned)v0.w << 16)) * 0x3F80u;
  r.u.z = ((unsigned)v1.x | ((unsigned)v1.y << 16)) * 0x3F80u;
  r.u.w = ((unsigned)v1.z | ((unsigned)v1.w << 16)) * 0x3F80u;
  return r.s;
}

#define LOADK(KT, PA, PB) {                                         \
    const int* ap_ = aptr0 + (KT) * 32;                             \
    PA[0] = *(const int4*)(ap_);                                    \
    PA[1] = *(const int4*)(ap_ + 4);                                \
    PA[2] = *(const int4*)(ap_ + 32768);                            \
    PA[3] = *(const int4*)(ap_ + 32768 + 4);                        \
    const char* bp_ = bbase + (size_t)(KT) * 64;                    \
    _Pragma("unroll")                                               \
    for (int nf_ = 0; nf_ < 9; ++nf_)                               \
      PB[nf_] = *(const short8*)(bp_ + (size_t)nf_ * 65536);        \
  }

#define COMPUTE(PA, PB) {                                                         \
    short8 af0_ = pack_a(PA[0], PA[1]);                                           \
    short8 af1_ = pack_a(PA[2], PA[3]);                                           \
    _Pragma("unroll")                                                             \
    for (int nf_ = 0; nf_ < 9; ++nf_) {                                           \
      acc[0][nf_] = __builtin_amdgcn_mfma_f32_16x16x32_bf16(af0_, PB[nf_], acc[0][nf_], 0, 0, 0); \
      acc[1][nf_] = __builtin_amdgcn_mfma_f32_16x16x32_bf16(af1_, PB[nf_], acc[1][nf_], 0, 0, 0); \
    }                                                                             \
  }

__global__ __launch_bounds__(256) void gat_main(
    const int* __restrict__ adj, const unsigned short* __restrict__ Bt,
    float* __restrict__ out) {
  __shared__ float denArr[64];
  const int bid = blockIdx.x;
  const int b   = bid & 7;     // batch pinned to XCD (bid % 8)
  const int rb  = bid >> 3;
  const int i0  = rb * 64;
  const int t   = threadIdx.x;
  const int w   = t >> 6, L = t & 63;
  const int wm  = w >> 1, wn = w & 1;
  const int kc  = L >> 4, fr = L & 15;

  // per-lane A source: row = i0 + wm*32 + (mf*16) + fr, k-chunk kc*8
  const int* __restrict__ aptr0 =
      adj + ((size_t)b * 2048 + i0 + wm * 32 + fr) * 2048 + kc * 8;
  // per-lane B source: col = wn*144 + (nf*16) + fr, 16B chunk kc within kt's 64B
  const char* __restrict__ bbase =
      (const char*)Bt + (size_t)b * 288 * 4096 + (size_t)(wn * 144 + fr) * 4096 + kc * 16;

  floatx4 acc[2][9];
#pragma unroll
  for (int i = 0; i < 2; ++i)
#pragma unroll
    for (int n = 0; n < 9; ++n) acc[i][n] = (floatx4)0.0f;

  int4   paA[4], paB[4];
  short8 pbA[9], pbB[9];
  LOADK(0, paA, pbA);
  LOADK(1, paB, pbB);

#pragma unroll 1
  for (int kt = 0; kt < 64; kt += 2) {
    COMPUTE(paA, pbA);
    if (kt + 2 < 64) { LOADK(kt + 2, paA, pbA); }
    COMPUTE(paB, pbB);
    if (kt + 3 < 64) { LOADK(kt + 3, paB, pbB); }
  }

  // epilogue: den = column 256 (held by wn==1, nf==7, fr==0 lanes)
  const int fq = L >> 4;
  if (wn == 1 && fr == 0) {
#pragma unroll
    for (int mf = 0; mf < 2; ++mf)
#pragma unroll
      for (int jj = 0; jj < 4; ++jj)
        denArr[wm * 32 + mf * 16 + fq * 4 + jj] = acc[mf][7][jj];
  }
  __syncthreads();
  float invd[2][4];
#pragma unroll
  for (int mf = 0; mf < 2; ++mf)
#pragma unroll
    for (int jj = 0; jj < 4; ++jj)
      invd[mf][jj] = 1.0f / denArr[wm * 32 + mf * 16 + fq * 4 + jj];
#pragma unroll
  for (int mf = 0; mf < 2; ++mf) {
#pragma unroll
    for (int nf = 0; nf < 9; ++nf) {
      int col = wn * 144 + nf * 16 + fr;
      if (col < 256) {
#pragma unroll
        for (int jj = 0; jj < 4; ++jj) {
          int r = wm * 32 + mf * 16 + fq * 4 + jj;
          float v = acc[mf][nf][jj] * invd[mf][jj];
          v = (v > 0.0f) ? v : expm1f(v);
          out[((size_t)b * 2048 + i0 + r) * 256 + col] = v;
        }
      }
    }
  }
}

extern "C" void kernel_launch(void* const* d_in, const int* in_sizes, int n_in,
                              void* d_out, int out_size, void* d_ws, size_t ws_size,
                              hipStream_t stream) {
  const float* h   = (const float*)d_in[0];
  const int*   adj = (const int*)d_in[1];
  const float* W   = (const float*)d_in[2];
  const float* a   = (const float*)d_in[3];
  float* out = (float*)d_out;

  char* ws = (char*)d_ws;
  if (ws_size < 26280192) return;  // need ~26.3 MB scratch
  float* Wh          = (float*)ws;                    // 16,777,216 B
  float* g           = (float*)(ws + 16777216);       //     65,536 B
  float* Mb          = (float*)(ws + 16842752);       //        256 B
  unsigned short* Bt = (unsigned short*)(ws + 16843008); // 9,437,184 B

  wh_gemm  <<<dim3(256, 2), 256, 0, stream>>>(h, W, Wh);
  g_rows   <<<4096,        256, 0, stream>>>(Wh, a, g);
  batch_max<<<8,           256, 0, stream>>>(g, Mb);
  build_bt <<<256,         256, 0, stream>>>(Wh, g, Mb, Bt);
  gat_main <<<256,         256, 0, stream>>>(adj, Bt, out);
}

// Round 4
// 124.765 us; speedup vs baseline: 1.2211x; 1.2211x over previous
//
#include <hip/hip_runtime.h>
#include <math.h>

using short8   = __attribute__((ext_vector_type(8))) short;
using floatx16 = __attribute__((ext_vector_type(16))) float;
using ushort4v = __attribute__((ext_vector_type(4))) unsigned short;

#define GLD16(gsrc, ldst) __builtin_amdgcn_global_load_lds( \
    (const __attribute__((address_space(1))) void*)(gsrc),  \
    (__attribute__((address_space(3))) void*)(ldst), 16, 0, 0)

__device__ __forceinline__ unsigned short f2bf(float x) {
  union { float f; unsigned u; } v; v.f = x;
  unsigned r = (v.u + 0x7FFFu + ((v.u >> 16) & 1u)) >> 16;
  return (unsigned short)r;
}
__device__ __forceinline__ float bf2f(unsigned short u) {
  union { unsigned u; float f; } v; v.u = ((unsigned)u) << 16;
  return v.f;
}
__device__ __forceinline__ short8 pack_a(int4 v0, int4 v1) {
  union { uint4 u; short8 s; } r;
  r.u.x = ((unsigned)v0.x | ((unsigned)v0.y << 16)) * 0x3F80u;
  r.u.y = ((unsigned)v0.z | ((unsigned)v0.w << 16)) * 0x3F80u;
  r.u.z = ((unsigned)v1.x | ((unsigned)v1.y << 16)) * 0x3F80u;
  r.u.w = ((unsigned)v1.z | ((unsigned)v1.w << 16)) * 0x3F80u;
  return r.s;
}

// ---------------- K1: Wh = h @ W  (f32 vector GEMM, bf16 output) ----------------
__global__ __launch_bounds__(256) void wh_gemm(
    const float* __restrict__ h, const float* __restrict__ W,
    unsigned short* __restrict__ Whb) {
  __shared__ __align__(16) float Al[16][64];    // [k][m]
  __shared__ __align__(16) float Bl[16][128];   // [k][n]
  const int m0 = blockIdx.x * 64;
  const int n0 = blockIdx.y * 128;
  const int t  = threadIdx.x;
  const int tx = t & 15, ty = t >> 4;
  float acc[4][8];
#pragma unroll
  for (int i = 0; i < 4; ++i)
#pragma unroll
    for (int j = 0; j < 8; ++j) acc[i][j] = 0.0f;

  for (int k0 = 0; k0 < 256; k0 += 16) {
    {
      int m = t & 63, kq = t >> 6;
      float4 v = *(const float4*)&h[(size_t)(m0 + m) * 256 + k0 + kq * 4];
      Al[kq * 4 + 0][m] = v.x; Al[kq * 4 + 1][m] = v.y;
      Al[kq * 4 + 2][m] = v.z; Al[kq * 4 + 3][m] = v.w;
    }
    {
      int n4 = t & 31, kr = t >> 5;
      *(float4*)&Bl[kr][n4 * 4]     = *(const float4*)&W[(size_t)(k0 + kr) * 256 + n0 + n4 * 4];
      *(float4*)&Bl[kr + 8][n4 * 4] = *(const float4*)&W[(size_t)(k0 + kr + 8) * 256 + n0 + n4 * 4];
    }
    __syncthreads();
#pragma unroll
    for (int k = 0; k < 16; ++k) {
      float4 av = *(const float4*)&Al[k][ty * 4];
      float4 b0 = *(const float4*)&Bl[k][tx * 4];
      float4 b1 = *(const float4*)&Bl[k][64 + tx * 4];
      float aa[4] = {av.x, av.y, av.z, av.w};
      float bb[8] = {b0.x, b0.y, b0.z, b0.w, b1.x, b1.y, b1.z, b1.w};
#pragma unroll
      for (int i = 0; i < 4; ++i)
#pragma unroll
        for (int j = 0; j < 8; ++j) acc[i][j] = fmaf(aa[i], bb[j], acc[i][j]);
    }
    __syncthreads();
  }
#pragma unroll
  for (int i = 0; i < 4; ++i) {
    size_t row = (size_t)(m0 + ty * 4 + i);
    ushort4v o0, o1;
#pragma unroll
    for (int j = 0; j < 4; ++j) { o0[j] = f2bf(acc[i][j]); o1[j] = f2bf(acc[i][4 + j]); }
    *(ushort4v*)&Whb[row * 256 + n0 + tx * 4]      = o0;
    *(ushort4v*)&Whb[row * 256 + n0 + 64 + tx * 4] = o1;
  }
}

// ---------------- K2a: g[row] = Wh[row,:] . a2 ----------------
__global__ __launch_bounds__(256) void g_rows(
    const unsigned short* __restrict__ Whb, const float* __restrict__ a,
    float* __restrict__ g) {
  int row = blockIdx.x * 4 + (threadIdx.x >> 6);
  int L = threadIdx.x & 63;
  ushort4v wv = *(const ushort4v*)&Whb[(size_t)row * 256 + L * 4];
  float4 av = *(const float4*)&a[256 + L * 4];
  float d = bf2f(wv[0]) * av.x + bf2f(wv[1]) * av.y + bf2f(wv[2]) * av.z + bf2f(wv[3]) * av.w;
#pragma unroll
  for (int off = 32; off > 0; off >>= 1) d += __shfl_xor(d, off);
  if (L == 0) g[row] = d;
}

// ---------------- K2b: per-batch max of g ----------------
__global__ __launch_bounds__(256) void batch_max(
    const float* __restrict__ g, float* __restrict__ Mb) {
  __shared__ float red[4];
  int b = blockIdx.x, t = threadIdx.x;
  float m = -1e30f;
  for (int i = t; i < 2048; i += 256) m = fmaxf(m, g[(size_t)b * 2048 + i]);
#pragma unroll
  for (int off = 32; off > 0; off >>= 1) m = fmaxf(m, __shfl_xor(m, off));
  if ((t & 63) == 0) red[t >> 6] = m;
  __syncthreads();
  if (t == 0) Mb[b] = fmaxf(fmaxf(red[0], red[1]), fmaxf(red[2], red[3]));
}

// ---------------- K2c: Bt[b][c][j] = bf16(s_j * Wh[b,j,c]); c=256 -> s_j; 257..319 -> 0
__global__ __launch_bounds__(256) void build_bt(
    const unsigned short* __restrict__ Whb, const float* __restrict__ g,
    const float* __restrict__ Mb, unsigned short* __restrict__ Bt) {
  __shared__ __align__(16) unsigned short tile[320 * 64];  // [c][j]
  const int blk = blockIdx.x;
  const int b   = blk >> 5;
  const int j0  = (blk & 31) * 64;
  const int t   = threadIdx.x;
  const int j   = t & 63;
  const int q0  = t >> 6;
  const int row = b * 2048 + j0 + j;
  const float s = expf(g[row] - Mb[b]);
  for (int q = q0; q < 64; q += 4) {
    ushort4v wv = *(const ushort4v*)&Whb[(size_t)row * 256 + q * 4];
    int c = q * 4;
    tile[(c + 0) * 64 + j] = f2bf(s * bf2f(wv[0]));
    tile[(c + 1) * 64 + j] = f2bf(s * bf2f(wv[1]));
    tile[(c + 2) * 64 + j] = f2bf(s * bf2f(wv[2]));
    tile[(c + 3) * 64 + j] = f2bf(s * bf2f(wv[3]));
  }
  if (q0 == 0) tile[256 * 64 + j] = f2bf(s);
  for (int z = t; z < 63 * 64; z += 256) tile[257 * 64 + z] = 0;
  __syncthreads();
#pragma unroll
  for (int p = 0; p < 10; ++p) {
    int id = t + 256 * p;          // 0..2559
    int c = id >> 3, off = id & 7;
    int4 v = *(const int4*)&tile[c * 64 + off * 8];
    *(int4*)((char*)Bt + (size_t)(b * 320 + c) * 4096 + j0 * 2 + off * 16) = v;
  }
}

// ---------------- K3: [num|den] = adj @ Bt^T with counted-vmcnt pipeline ----------------
// grid 256 (b=bid&7 XCD-pinned, rb=bid>>3). BM=64, BN=320, BK=32, 4 waves (2x2),
// 32x32x16 MFMA, triple-buffered LDS (28KB/tile), 7 gld_lds per wave per tile,
// s_waitcnt vmcnt(7) steady state (never 0 in loop).
__global__ __launch_bounds__(256) void gat_main(
    const int* __restrict__ adj, const unsigned short* __restrict__ Bt,
    float* __restrict__ out) {
  __shared__ __align__(16) char lds[86272];  // 3 x (8KB A + 20KB B) + 256B den
  const int bid = blockIdx.x;
  const int b   = bid & 7;
  const int rb  = bid >> 3;
  const int i0  = rb * 64;
  const int tid = threadIdx.x;
  const int w   = tid >> 6, L = tid & 63;
  const int wm  = w >> 1, wn = w & 1;
  const int hi  = L >> 5;
  const int r31 = L & 31;

  const char* adjB = (const char*)adj + ((size_t)b * 2048 + i0) * 8192;
  const char* BtB  = (const char*)Bt  + (size_t)b * 1310720;

  // A staging source: gld g covers rows g*8..+7 (128B rows), 8 slots of 16B,
  // slot pre-swizzled by ^(row&7) so LDS-linear == swizzled layout.
  const char* asrc0 = adjB + (size_t)(w * 8 + (L >> 3)) * 8192 + (((L & 7) ^ (L >> 3)) << 4);
  const char* asrc1 = asrc0 + (size_t)32 * 8192;
  // B staging source: gld g covers cols g*16..+15 (64B per col per tile), 4 slots,
  // slot pre-swizzled by ^((c&3)^((c>>2)&1)).
  const char* bsrc0 = BtB + (size_t)(w * 16 + (L >> 2)) * 4096
                    + ((((L & 3) ^ ((L >> 2) & 3)) ^ ((L >> 4) & 1)) << 4);

  floatx16 acc[5];
#pragma unroll
  for (int nf = 0; nf < 5; ++nf) acc[nf] = (floatx16)0.0f;

  const int sx = (L & 3) ^ ((L >> 2) & 1);   // B-read swizzle component

#define STAGE(TT, BASE) {                                  \
    size_t ao_ = (size_t)(TT) * 128;                       \
    size_t bo_ = (size_t)(TT) * 64;                        \
    char* Ab_ = (BASE);                                    \
    char* Bb_ = (BASE) + 8192;                             \
    GLD16(asrc0 + ao_, Ab_ + w * 1024);                    \
    GLD16(asrc1 + ao_, Ab_ + (w + 4) * 1024);              \
    GLD16(bsrc0 + bo_,           Bb_ + w * 1024);          \
    GLD16(bsrc0 + bo_ +  262144, Bb_ + (w + 4) * 1024);    \
    GLD16(bsrc0 + bo_ +  524288, Bb_ + (w + 8) * 1024);    \
    GLD16(bsrc0 + bo_ +  786432, Bb_ + (w + 12) * 1024);   \
    GLD16(bsrc0 + bo_ + 1048576, Bb_ + (w + 16) * 1024);   \
  }

#define COMPUTE(BASE) {                                                          \
    const char* arow_ = (BASE) + (wm * 32 + r31) * 128;                          \
    const char* bcol_ = (BASE) + 8192 + (wn * 160 + r31) * 64;                   \
    _Pragma("unroll")                                                            \
    for (int kk = 0; kk < 2; ++kk) {                                             \
      int sb_ = kk * 4 + hi * 2;                                                 \
      int4 a0_ = *(const int4*)(arow_ + (((sb_ + 0) ^ (L & 7)) << 4));           \
      int4 a1_ = *(const int4*)(arow_ + (((sb_ + 1) ^ (L & 7)) << 4));           \
      short8 af_ = pack_a(a0_, a1_);                                             \
      int sl_ = ((kk * 2 + hi) ^ sx) << 4;                                       \
      _Pragma("unroll")                                                          \
      for (int nf = 0; nf < 5; ++nf) {                                           \
        short8 bf_ = *(const short8*)(bcol_ + nf * 2048 + sl_);                  \
        acc[nf] = __builtin_amdgcn_mfma_f32_32x32x16_bf16(af_, bf_, acc[nf], 0, 0, 0); \
      }                                                                          \
    }                                                                            \
  }

#define PHASE(CURBASE, STTT, STBASE, GUARD) {              \
    asm volatile("s_waitcnt vmcnt(7)" ::: "memory");       \
    __builtin_amdgcn_s_barrier();                          \
    asm volatile("" ::: "memory");                         \
    if (GUARD) STAGE(STTT, STBASE);                        \
    COMPUTE(CURBASE);                                      \
  }

  STAGE(0, lds);
  STAGE(1, lds + 28672);

#pragma unroll 1
  for (int tt = 0; tt < 63; tt += 3) {
    PHASE(lds,         tt + 2, lds + 57344, true);
    PHASE(lds + 28672, tt + 3, lds,         (tt + 3 < 64));
    PHASE(lds + 57344, tt + 4, lds + 28672, (tt + 4 < 64));
  }
  asm volatile("s_waitcnt vmcnt(0)" ::: "memory");
  __builtin_amdgcn_s_barrier();
  asm volatile("" ::: "memory");
  COMPUTE(lds);   // tile 63 -> buffer 0 (63 % 3 == 0)

  // epilogue: den = column 256 = (wn==1, nf==3, lane&31==0)
  float* denL = (float*)(lds + 86016);
  if (wn == 1 && r31 == 0) {
#pragma unroll
    for (int rg = 0; rg < 16; ++rg) {
      int row = (rg & 3) + 8 * (rg >> 2) + 4 * hi;
      denL[wm * 32 + row] = acc[3][rg];
    }
  }
  __syncthreads();
  float invd[16];
#pragma unroll
  for (int rg = 0; rg < 16; ++rg) {
    int row = (rg & 3) + 8 * (rg >> 2) + 4 * hi;
    invd[rg] = 1.0f / denL[wm * 32 + row];
  }
#pragma unroll
  for (int nf = 0; nf < 5; ++nf) {
    int cb = wn * 160 + nf * 32;
    if (cb < 256) {
#pragma unroll
      for (int rg = 0; rg < 16; ++rg) {
        int row = (rg & 3) + 8 * (rg >> 2) + 4 * hi;
        float v = acc[nf][rg] * invd[rg];
        v = (v > 0.0f) ? v : expm1f(v);
        out[((size_t)b * 2048 + i0 + wm * 32 + row) * 256 + cb + r31] = v;
      }
    }
  }
#undef PHASE
#undef COMPUTE
#undef STAGE
}

extern "C" void kernel_launch(void* const* d_in, const int* in_sizes, int n_in,
                              void* d_out, int out_size, void* d_ws, size_t ws_size,
                              hipStream_t stream) {
  const float* h   = (const float*)d_in[0];
  const int*   adj = (const int*)d_in[1];
  const float* W   = (const float*)d_in[2];
  const float* a   = (const float*)d_in[3];
  float* out = (float*)d_out;

  char* ws = (char*)d_ws;
  if (ws_size < 18940160) return;  // Whb 8.39M + g 64K + Mb + Bt 10.49M
  unsigned short* Whb = (unsigned short*)ws;             // 8,388,608 B
  float* g            = (float*)(ws + 8388608);          //    65,536 B
  float* Mb           = (float*)(ws + 8454144);          //       256 B
  unsigned short* Bt  = (unsigned short*)(ws + 8454400); // 10,485,760 B

  wh_gemm  <<<dim3(256, 2), 256, 0, stream>>>(h, W, Whb);
  g_rows   <<<4096,        256, 0, stream>>>(Whb, a, g);
  batch_max<<<8,           256, 0, stream>>>(g, Mb);
  build_bt <<<256,         256, 0, stream>>>(Whb, g, Mb, Bt);
  gat_main <<<256,         256, 0, stream>>>(adj, Bt, out);
}

// Round 5
// 103.316 us; speedup vs baseline: 1.4746x; 1.2076x over previous
//
#include <hip/hip_runtime.h>
#include <math.h>

using short8   = __attribute__((ext_vector_type(8))) short;
using floatx4  = __attribute__((ext_vector_type(4))) float;
using ushort4v = __attribute__((ext_vector_type(4))) unsigned short;

#define GLD16(gsrc, ldst) __builtin_amdgcn_global_load_lds( \
    (const __attribute__((address_space(1))) void*)(gsrc),  \
    (__attribute__((address_space(3))) void*)(ldst), 16, 0, 0)

__device__ __forceinline__ unsigned short f2bf(float x) {
  union { float f; unsigned u; } v; v.f = x;
  unsigned r = (v.u + 0x7FFFu + ((v.u >> 16) & 1u)) >> 16;
  return (unsigned short)r;
}
__device__ __forceinline__ float bf2f(unsigned short u) {
  union { unsigned u; float f; } v; v.u = ((unsigned)u) << 16;
  return v.f;
}
__device__ __forceinline__ short8 pack_a(int4 v0, int4 v1) {
  union { uint4 u; short8 s; } r;
  r.u.x = ((unsigned)v0.x | ((unsigned)v0.y << 16)) * 0x3F80u;
  r.u.y = ((unsigned)v0.z | ((unsigned)v0.w << 16)) * 0x3F80u;
  r.u.z = ((unsigned)v1.x | ((unsigned)v1.y << 16)) * 0x3F80u;
  r.u.w = ((unsigned)v1.z | ((unsigned)v1.w << 16)) * 0x3F80u;
  return r.s;
}

// ---------------- K1: Wh = h @ W  (f32 vector GEMM, bf16 output) ----------------
__global__ __launch_bounds__(256) void wh_gemm(
    const float* __restrict__ h, const float* __restrict__ W,
    unsigned short* __restrict__ Whb) {
  __shared__ __align__(16) float Al[16][64];
  __shared__ __align__(16) float Bl[16][128];
  const int m0 = blockIdx.x * 64;
  const int n0 = blockIdx.y * 128;
  const int t  = threadIdx.x;
  const int tx = t & 15, ty = t >> 4;
  float acc[4][8];
#pragma unroll
  for (int i = 0; i < 4; ++i)
#pragma unroll
    for (int j = 0; j < 8; ++j) acc[i][j] = 0.0f;

  for (int k0 = 0; k0 < 256; k0 += 16) {
    {
      int m = t & 63, kq = t >> 6;
      float4 v = *(const float4*)&h[(size_t)(m0 + m) * 256 + k0 + kq * 4];
      Al[kq * 4 + 0][m] = v.x; Al[kq * 4 + 1][m] = v.y;
      Al[kq * 4 + 2][m] = v.z; Al[kq * 4 + 3][m] = v.w;
    }
    {
      int n4 = t & 31, kr = t >> 5;
      *(float4*)&Bl[kr][n4 * 4]     = *(const float4*)&W[(size_t)(k0 + kr) * 256 + n0 + n4 * 4];
      *(float4*)&Bl[kr + 8][n4 * 4] = *(const float4*)&W[(size_t)(k0 + kr + 8) * 256 + n0 + n4 * 4];
    }
    __syncthreads();
#pragma unroll
    for (int k = 0; k < 16; ++k) {
      float4 av = *(const float4*)&Al[k][ty * 4];
      float4 b0 = *(const float4*)&Bl[k][tx * 4];
      float4 b1 = *(const float4*)&Bl[k][64 + tx * 4];
      float aa[4] = {av.x, av.y, av.z, av.w};
      float bb[8] = {b0.x, b0.y, b0.z, b0.w, b1.x, b1.y, b1.z, b1.w};
#pragma unroll
      for (int i = 0; i < 4; ++i)
#pragma unroll
        for (int j = 0; j < 8; ++j) acc[i][j] = fmaf(aa[i], bb[j], acc[i][j]);
    }
    __syncthreads();
  }
#pragma unroll
  for (int i = 0; i < 4; ++i) {
    size_t row = (size_t)(m0 + ty * 4 + i);
    ushort4v o0, o1;
#pragma unroll
    for (int j = 0; j < 4; ++j) { o0[j] = f2bf(acc[i][j]); o1[j] = f2bf(acc[i][4 + j]); }
    *(ushort4v*)&Whb[row * 256 + n0 + tx * 4]      = o0;
    *(ushort4v*)&Whb[row * 256 + n0 + 64 + tx * 4] = o1;
  }
}

// ---------------- K2a: g[row] = Wh[row,:] . a2 ----------------
__global__ __launch_bounds__(256) void g_rows(
    const unsigned short* __restrict__ Whb, const float* __restrict__ a,
    float* __restrict__ g) {
  int row = blockIdx.x * 4 + (threadIdx.x >> 6);
  int L = threadIdx.x & 63;
  ushort4v wv = *(const ushort4v*)&Whb[(size_t)row * 256 + L * 4];
  float4 av = *(const float4*)&a[256 + L * 4];
  float d = bf2f(wv[0]) * av.x + bf2f(wv[1]) * av.y + bf2f(wv[2]) * av.z + bf2f(wv[3]) * av.w;
#pragma unroll
  for (int off = 32; off > 0; off >>= 1) d += __shfl_xor(d, off);
  if (L == 0) g[row] = d;
}

// ---------------- K2b: per-batch max of g ----------------
__global__ __launch_bounds__(256) void batch_max(
    const float* __restrict__ g, float* __restrict__ Mb) {
  __shared__ float red[4];
  int b = blockIdx.x, t = threadIdx.x;
  float m = -1e30f;
  for (int i = t; i < 2048; i += 256) m = fmaxf(m, g[(size_t)b * 2048 + i]);
#pragma unroll
  for (int off = 32; off > 0; off >>= 1) m = fmaxf(m, __shfl_xor(m, off));
  if ((t & 63) == 0) red[t >> 6] = m;
  __syncthreads();
  if (t == 0) Mb[b] = fmaxf(fmaxf(red[0], red[1]), fmaxf(red[2], red[3]));
}

// ---------------- K2c: tile-contiguous swizzled B:
// Bt2[((b*64 + kt)*320 + c)*64B], 64B = k-slot-swizzled 32 bf16 of s_j*Wh[b,j,c]
// (c==256 -> s_j; 257..319 -> 0)
__global__ __launch_bounds__(256) void build_bt(
    const unsigned short* __restrict__ Whb, const float* __restrict__ g,
    const float* __restrict__ Mb, unsigned short* __restrict__ Bt) {
  __shared__ __align__(16) unsigned short tile[320 * 64];  // [c][j]
  const int blk = blockIdx.x;
  const int b   = blk >> 5;
  const int j0  = (blk & 31) * 64;
  const int kt_base = (blk & 31) * 2;
  const int t   = threadIdx.x;
  const int j   = t & 63;
  const int q0  = t >> 6;
  const int row = b * 2048 + j0 + j;
  const float s = expf(g[row] - Mb[b]);
  for (int q = q0; q < 64; q += 4) {
    ushort4v wv = *(const ushort4v*)&Whb[(size_t)row * 256 + q * 4];
    int c = q * 4;
    tile[(c + 0) * 64 + j] = f2bf(s * bf2f(wv[0]));
    tile[(c + 1) * 64 + j] = f2bf(s * bf2f(wv[1]));
    tile[(c + 2) * 64 + j] = f2bf(s * bf2f(wv[2]));
    tile[(c + 3) * 64 + j] = f2bf(s * bf2f(wv[3]));
  }
  if (q0 == 0) tile[256 * 64 + j] = f2bf(s);
  for (int z = t; z < 63 * 64; z += 256) tile[257 * 64 + z] = 0;
  __syncthreads();
#pragma unroll
  for (int p = 0; p < 10; ++p) {
    int id = t + 256 * p;          // 0..2559 -> (c, off)
    int c = id >> 3, off = id & 7;
    int kt_l = off >> 2, slot = off & 3;
    int sw = slot ^ ((c >> 1) & 3);
    size_t dst = ((size_t)((b * 64 + kt_base + kt_l) * 320 + c)) * 64 + (sw << 4);
    *(int4*)((char*)Bt + dst) = *(const int4*)&tile[c * 64 + off * 8];
  }
}

// ---------------- K3: [num|den] = adj @ Bt2^T ----------------
// grid 512 (b=bid&7 XCD-pinned, 2 blocks/CU). BM=32, BN=320, BK=32, 4 waves
// (wave w owns cols w*80..+79; 2 M-frags x 5 N-frags of 16x16x32 MFMA).
// Triple-buffered LDS (24KB/tile), 6 gld_lds/wave/tile, vmcnt(6) counted.
__global__ __launch_bounds__(256, 2) void gat_main(
    const int* __restrict__ adj, const unsigned short* __restrict__ Bt,
    float* __restrict__ out) {
  __shared__ __align__(16) char lds[73856];  // 3 x (4KB A + 20KB B) + 128B den
  const int bid = blockIdx.x;
  const int b   = bid & 7;
  const int rb  = bid >> 3;
  const int i0  = rb * 32;
  const int tid = threadIdx.x;
  const int w   = tid >> 6, L = tid & 63;
  const int fr  = L & 15, kc = L >> 4;

  const char* adjB = (const char*)adj + ((size_t)b * 2048 + i0) * 8192;
  const char* BtB  = (const char*)Bt  + (size_t)b * 1310720;

  // A staging: wave w covers rows w*8..w*8+7; slot pre-swizzled ^(row&7)
  const char* asrc = adjB + (size_t)(w * 8 + (L >> 3)) * 8192 + (((L & 7) ^ (L >> 3)) << 4);
  // B staging: pure linear copy of the 20KB tile (pre-swizzled at build)
  const char* bsrc = BtB + (size_t)(w * 5) * 1024 + L * 16;

  floatx4 acc[2][5];
#pragma unroll
  for (int i = 0; i < 2; ++i)
#pragma unroll
    for (int n = 0; n < 5; ++n) acc[i][n] = (floatx4)0.0f;

#define STAGE(TT, BASE) {                                   \
    char* Ab_ = (BASE);                                     \
    char* Bb_ = (BASE) + 4096;                              \
    GLD16(asrc + (size_t)(TT) * 128, Ab_ + w * 1024);       \
    const char* bs_ = bsrc + (size_t)(TT) * 20480;          \
    GLD16(bs_,        Bb_ + (w * 5 + 0) * 1024);            \
    GLD16(bs_ + 1024, Bb_ + (w * 5 + 1) * 1024);            \
    GLD16(bs_ + 2048, Bb_ + (w * 5 + 2) * 1024);            \
    GLD16(bs_ + 3072, Bb_ + (w * 5 + 3) * 1024);            \
    GLD16(bs_ + 4096, Bb_ + (w * 5 + 4) * 1024);            \
  }

#define COMPUTE(BASE) {                                                          \
    const char* Ab_ = (BASE);                                                    \
    const char* Bb_ = (BASE) + 4096;                                             \
    short8 af_[2];                                                               \
    _Pragma("unroll")                                                            \
    for (int mf = 0; mf < 2; ++mf) {                                             \
      int row_ = mf * 16 + fr;                                                   \
      const char* ar_ = Ab_ + row_ * 128;                                        \
      int4 a0_ = *(const int4*)(ar_ + (((2 * kc)     ^ (fr & 7)) << 4));         \
      int4 a1_ = *(const int4*)(ar_ + (((2 * kc + 1) ^ (fr & 7)) << 4));         \
      af_[mf] = pack_a(a0_, a1_);                                                \
    }                                                                            \
    _Pragma("unroll")                                                            \
    for (int nf = 0; nf < 5; ++nf) {                                             \
      int col_ = w * 80 + nf * 16 + fr;                                          \
      short8 bf_ = *(const short8*)(Bb_ + col_ * 64 + ((kc ^ ((col_ >> 1) & 3)) << 4)); \
      acc[0][nf] = __builtin_amdgcn_mfma_f32_16x16x32_bf16(af_[0], bf_, acc[0][nf], 0, 0, 0); \
      acc[1][nf] = __builtin_amdgcn_mfma_f32_16x16x32_bf16(af_[1], bf_, acc[1][nf], 0, 0, 0); \
    }                                                                            \
  }

#define PHASE(CURBASE, STTT, STBASE, GUARD) {              \
    asm volatile("s_waitcnt vmcnt(6)" ::: "memory");       \
    __builtin_amdgcn_s_barrier();                          \
    if (GUARD) STAGE(STTT, STBASE);                        \
    COMPUTE(CURBASE);                                      \
  }

  STAGE(0, lds);
  STAGE(1, lds + 24576);

#pragma unroll 1
  for (int tt = 0; tt < 63; tt += 3) {
    PHASE(lds,         tt + 2, lds + 49152, true);
    PHASE(lds + 24576, tt + 3, lds,         (tt + 3 < 64));
    PHASE(lds + 49152, tt + 4, lds + 24576, (tt + 4 < 64));
  }
  asm volatile("s_waitcnt vmcnt(0)" ::: "memory");
  __builtin_amdgcn_s_barrier();
  COMPUTE(lds);   // tile 63 -> buffer 0 (63 % 3 == 0)

  // epilogue: den = col 256 -> wave 3, nf==1, fr==0
  float* denL = (float*)(lds + 73728);
  const int q = L >> 4;
  if (w == 3 && fr == 0) {
#pragma unroll
    for (int mf = 0; mf < 2; ++mf)
#pragma unroll
      for (int jj = 0; jj < 4; ++jj)
        denL[mf * 16 + q * 4 + jj] = acc[mf][1][jj];
  }
  __syncthreads();
  float invd[2][4];
#pragma unroll
  for (int mf = 0; mf < 2; ++mf)
#pragma unroll
    for (int jj = 0; jj < 4; ++jj)
      invd[mf][jj] = 1.0f / denL[mf * 16 + q * 4 + jj];
#pragma unroll
  for (int mf = 0; mf < 2; ++mf) {
#pragma unroll
    for (int nf = 0; nf < 5; ++nf) {
      int col = w * 80 + nf * 16 + fr;
      if (col < 256) {
#pragma unroll
        for (int jj = 0; jj < 4; ++jj) {
          int row = mf * 16 + q * 4 + jj;
          float v = acc[mf][nf][jj] * invd[mf][jj];
          v = (v > 0.0f) ? v : expm1f(v);
          out[((size_t)b * 2048 + i0 + row) * 256 + col] = v;
        }
      }
    }
  }
#undef PHASE
#undef COMPUTE
#undef STAGE
}

extern "C" void kernel_launch(void* const* d_in, const int* in_sizes, int n_in,
                              void* d_out, int out_size, void* d_ws, size_t ws_size,
                              hipStream_t stream) {
  const float* h   = (const float*)d_in[0];
  const int*   adj = (const int*)d_in[1];
  const float* W   = (const float*)d_in[2];
  const float* a   = (const float*)d_in[3];
  float* out = (float*)d_out;

  char* ws = (char*)d_ws;
  if (ws_size < 18940160) return;
  unsigned short* Whb = (unsigned short*)ws;             // 8,388,608 B
  float* g            = (float*)(ws + 8388608);          //    65,536 B
  float* Mb           = (float*)(ws + 8454144);          //       256 B
  unsigned short* Bt  = (unsigned short*)(ws + 8454400); // 10,485,760 B

  wh_gemm  <<<dim3(256, 2), 256, 0, stream>>>(h, W, Whb);
  g_rows   <<<4096,        256, 0, stream>>>(Whb, a, g);
  batch_max<<<8,           256, 0, stream>>>(g, Mb);
  build_bt <<<256,         256, 0, stream>>>(Whb, g, Mb, Bt);
  gat_main <<<512,         256, 0, stream>>>(adj, Bt, out);
}